// Round 1
// baseline (623.703 us; speedup 1.0000x reference)
//
#include <hip/hip_runtime.h>
#include <hip/hip_bf16.h>
#include <math.h>

#define DIN 128
#define DH 64
#define DOUT_ 16

// ---------------- degree accumulation ----------------
__global__ void deg_kernel(const int* __restrict__ dst, const float* __restrict__ ew,
                           float* __restrict__ deg, int E) {
    int e = blockIdx.x * blockDim.x + threadIdx.x;
    int stride = gridDim.x * blockDim.x;
    for (; e < E; e += stride) atomicAdd(&deg[dst[e]], ew[e]);
}

__global__ void dinv_kernel(float* __restrict__ deg, int N) {
    int i = blockIdx.x * blockDim.x + threadIdx.x;
    if (i < N) deg[i] = rsqrtf(deg[i] + 1.0f);
}

__global__ void norm_kernel(const int* __restrict__ src, const int* __restrict__ dst,
                            const float* __restrict__ ew, const float* __restrict__ dinv,
                            float* __restrict__ norm, int E) {
    int e = blockIdx.x * blockDim.x + threadIdx.x;
    int stride = gridDim.x * blockDim.x;
    for (; e < E; e += stride)
        norm[e] = dinv[src[e]] * ew[e] * dinv[dst[e]];
}

// ---------------- GEMM: X[N,K] @ W[K,64] -> H[N,64] ----------------
template <int K>
__global__ __launch_bounds__(256) void gemm_x64(const float* __restrict__ X,
                                                const float* __restrict__ W,
                                                float* __restrict__ H, int N) {
    __shared__ float Ws[K * 64];
    for (int idx = threadIdx.x; idx < K * 64 / 4; idx += 256)
        ((float4*)Ws)[idx] = ((const float4*)W)[idx];
    __syncthreads();

    const int tr = threadIdx.x >> 4;   // 0..15 (row group of 4)
    const int tc = threadIdx.x & 15;   // 0..15 (col group of 4)
    const int rowBase = blockIdx.x * 64 + tr * 4;

    float4 acc[4];
    #pragma unroll
    for (int i = 0; i < 4; i++) acc[i] = make_float4(0.f, 0.f, 0.f, 0.f);

    const float4* X4 = (const float4*)X;
    const float4* Ws4 = (const float4*)Ws;
    bool v[4];
    #pragma unroll
    for (int i = 0; i < 4; i++) v[i] = (rowBase + i) < N;

    for (int kk = 0; kk < K; kk += 4) {
        float4 a[4];
        #pragma unroll
        for (int i = 0; i < 4; i++)
            a[i] = v[i] ? X4[(long long)(rowBase + i) * (K / 4) + (kk >> 2)]
                        : make_float4(0.f, 0.f, 0.f, 0.f);
        #pragma unroll
        for (int t = 0; t < 4; t++) {
            float4 b = Ws4[(kk + t) * 16 + tc];
            #pragma unroll
            for (int i = 0; i < 4; i++) {
                float av = (t == 0) ? a[i].x : (t == 1) ? a[i].y : (t == 2) ? a[i].z : a[i].w;
                acc[i].x += av * b.x;
                acc[i].y += av * b.y;
                acc[i].z += av * b.z;
                acc[i].w += av * b.w;
            }
        }
    }
    float4* H4 = (float4*)H;
    #pragma unroll
    for (int i = 0; i < 4; i++)
        if (v[i]) H4[(long long)(rowBase + i) * 16 + tc] = acc[i];
}

// ---------------- GEMM: X[N,64] @ W[64,16] -> H[N,16] ----------------
__global__ __launch_bounds__(256) void gemm_64x16(const float* __restrict__ X,
                                                  const float* __restrict__ W,
                                                  float* __restrict__ H, int N) {
    __shared__ float Ws[64 * 16];
    for (int idx = threadIdx.x; idx < 64 * 16 / 4; idx += 256)
        ((float4*)Ws)[idx] = ((const float4*)W)[idx];
    __syncthreads();

    const int tr = threadIdx.x >> 2;  // 0..63 row
    const int tc = threadIdx.x & 3;   // 0..3 col group of 4
    const int row = blockIdx.x * 64 + tr;
    if (row >= N) return;

    float4 acc = make_float4(0.f, 0.f, 0.f, 0.f);
    const float4* X4 = (const float4*)X;
    const float4* Ws4 = (const float4*)Ws;
    for (int kk = 0; kk < 64; kk += 4) {
        float4 a = X4[(long long)row * 16 + (kk >> 2)];
        #pragma unroll
        for (int t = 0; t < 4; t++) {
            float4 b = Ws4[(kk + t) * 4 + tc];
            float av = (t == 0) ? a.x : (t == 1) ? a.y : (t == 2) ? a.z : a.w;
            acc.x += av * b.x;
            acc.y += av * b.y;
            acc.z += av * b.z;
            acc.w += av * b.w;
        }
    }
    ((float4*)H)[(long long)row * 4 + tc] = acc;
}

// ---------------- edge scatter: agg[dst] += h[src] * norm ----------------
template <int F>
__global__ void scatter_kernel(const float* __restrict__ h, const float* __restrict__ norm,
                               const int* __restrict__ src, const int* __restrict__ dst,
                               float* __restrict__ agg, int E) {
    long long g = (long long)blockIdx.x * blockDim.x + threadIdx.x;
    int f = (int)(g % F);
    long long e = g / F;
    long long estride = (long long)gridDim.x * blockDim.x / F;
    for (; e < E; e += estride) {
        int s = src[e];
        int d = dst[e];
        float w = norm[e];
        atomicAdd(&agg[(long long)d * F + f], h[(long long)s * F + f] * w);
    }
}

// ---------------- self-loop + bias (+relu), in place on agg ----------------
template <int F, bool RELU>
__global__ void selfloop_kernel(float* __restrict__ agg, const float* __restrict__ h,
                                const float* __restrict__ dinv, const float* __restrict__ b,
                                int N) {
    const int F4 = F / 4;
    long long idx = (long long)blockIdx.x * blockDim.x + threadIdx.x;
    long long total = (long long)N * F4;
    if (idx >= total) return;
    int node = (int)(idx / F4);
    int f4 = (int)(idx % F4);
    float di = dinv[node];
    float d2 = di * di;
    float4 a = ((const float4*)agg)[idx];
    float4 hv = ((const float4*)h)[idx];
    float4 bv = ((const float4*)b)[f4];
    float4 r;
    r.x = a.x + hv.x * d2 + bv.x;
    r.y = a.y + hv.y * d2 + bv.y;
    r.z = a.z + hv.z * d2 + bv.z;
    r.w = a.w + hv.w * d2 + bv.w;
    if (RELU) {
        r.x = fmaxf(r.x, 0.f);
        r.y = fmaxf(r.y, 0.f);
        r.z = fmaxf(r.z, 0.f);
        r.w = fmaxf(r.w, 0.f);
    }
    ((float4*)agg)[idx] = r;
}

// ---------------- final: self-loop + bias + log_softmax ----------------
__global__ void final_kernel(float* __restrict__ out, const float* __restrict__ h3,
                             const float* __restrict__ dinv, const float* __restrict__ b3,
                             int N) {
    int i = blockIdx.x * blockDim.x + threadIdx.x;
    if (i >= N) return;
    float di = dinv[i];
    float d2 = di * di;
    float z[16];
    const float4* o4 = (const float4*)out + (long long)i * 4;
    const float4* h4 = (const float4*)h3 + (long long)i * 4;
    const float4* b4 = (const float4*)b3;
    #pragma unroll
    for (int j = 0; j < 4; j++) {
        float4 a = o4[j], hv = h4[j], bv = b4[j];
        z[4 * j + 0] = a.x + hv.x * d2 + bv.x;
        z[4 * j + 1] = a.y + hv.y * d2 + bv.y;
        z[4 * j + 2] = a.z + hv.z * d2 + bv.z;
        z[4 * j + 3] = a.w + hv.w * d2 + bv.w;
    }
    float m = z[0];
    #pragma unroll
    for (int k = 1; k < 16; k++) m = fmaxf(m, z[k]);
    float s = 0.f;
    #pragma unroll
    for (int k = 0; k < 16; k++) s += expf(z[k] - m);
    float l = logf(s) + m;
    float4* w4 = (float4*)out + (long long)i * 4;
    #pragma unroll
    for (int j = 0; j < 4; j++) {
        float4 r;
        r.x = z[4 * j + 0] - l;
        r.y = z[4 * j + 1] - l;
        r.z = z[4 * j + 2] - l;
        r.w = z[4 * j + 3] - l;
        w4[j] = r;
    }
}

extern "C" void kernel_launch(void* const* d_in, const int* in_sizes, int n_in,
                              void* d_out, int out_size, void* d_ws, size_t ws_size,
                              hipStream_t stream) {
    const float* x = (const float*)d_in[0];
    const int* ei = (const int*)d_in[1];
    const float* ew = (const float*)d_in[2];
    const float* W1 = (const float*)d_in[3];
    const float* b1 = (const float*)d_in[4];
    const float* W2 = (const float*)d_in[5];
    const float* b2 = (const float*)d_in[6];
    const float* W3 = (const float*)d_in[7];
    const float* b3 = (const float*)d_in[8];

    const int N = in_sizes[0] / DIN;
    const int E = in_sizes[2];
    const int* src = ei;
    const int* dst = ei + E;

    float* out = (float*)d_out;

    // workspace layout (floats)
    float* A = (float*)d_ws;                       // h buffer [N,64]
    float* B = A + (long long)N * DH;              // agg/out buffer [N,64]
    float* C = B + (long long)N * DH;              // h3 [N,16]
    float* dinv = C + (long long)N * DOUT_;        // [N]
    float* nrm = dinv + N;                         // [E]

    const int TB = 256;
    const int edgeBlocks = (E + TB - 1) / TB;
    const int nodeBlocks = (N + TB - 1) / TB;
    const int rowBlocks = (N + 63) / 64;

    // --- degrees & norm ---
    hipMemsetAsync(dinv, 0, (size_t)N * sizeof(float), stream);
    deg_kernel<<<edgeBlocks, TB, 0, stream>>>(dst, ew, dinv, E);
    dinv_kernel<<<nodeBlocks, TB, 0, stream>>>(dinv, N);
    norm_kernel<<<edgeBlocks, TB, 0, stream>>>(src, dst, ew, dinv, nrm, E);

    // --- layer 1 ---
    gemm_x64<DIN><<<rowBlocks, TB, 0, stream>>>(x, W1, A, N);
    hipMemsetAsync(B, 0, (size_t)N * DH * sizeof(float), stream);
    scatter_kernel<DH><<<4096, TB, 0, stream>>>(A, nrm, src, dst, B, E);
    {
        long long tot = (long long)N * (DH / 4);
        selfloop_kernel<DH, true><<<(int)((tot + TB - 1) / TB), TB, 0, stream>>>(B, A, dinv, b1, N);
    }

    // --- layer 2 ---
    gemm_x64<DH><<<rowBlocks, TB, 0, stream>>>(B, W2, A, N);
    hipMemsetAsync(B, 0, (size_t)N * DH * sizeof(float), stream);
    scatter_kernel<DH><<<4096, TB, 0, stream>>>(A, nrm, src, dst, B, E);
    {
        long long tot = (long long)N * (DH / 4);
        selfloop_kernel<DH, true><<<(int)((tot + TB - 1) / TB), TB, 0, stream>>>(B, A, dinv, b2, N);
    }

    // --- layer 3 ---
    gemm_64x16<<<rowBlocks, TB, 0, stream>>>(B, W3, C, N);
    hipMemsetAsync(out, 0, (size_t)N * DOUT_ * sizeof(float), stream);
    scatter_kernel<DOUT_><<<4096, TB, 0, stream>>>(C, nrm, src, dst, out, E);
    final_kernel<<<nodeBlocks, TB, 0, stream>>>(out, C, dinv, b3, N);
}

// Round 2
// 408.261 us; speedup vs baseline: 1.5277x; 1.5277x over previous
//
#include <hip/hip_runtime.h>
#include <hip/hip_bf16.h>
#include <math.h>

#define DIN 128
#define DH 64
#define DOUT_ 16

typedef long long ll;

// ---------------- degree (weighted) + count ----------------
__global__ void deg_kernel(const int* __restrict__ dst, const float* __restrict__ ew,
                           float* __restrict__ deg, int* __restrict__ cnt, int E) {
    int e = blockIdx.x * blockDim.x + threadIdx.x;
    int stride = gridDim.x * blockDim.x;
    for (; e < E; e += stride) {
        int d = dst[e];
        atomicAdd(&deg[d], ew[e]);
        atomicAdd(&cnt[d], 1);
    }
}

__global__ void dinv_kernel(float* __restrict__ deg, int N) {
    int i = blockIdx.x * blockDim.x + threadIdx.x;
    if (i < N) deg[i] = rsqrtf(deg[i] + 1.0f);
}

// ---------------- two-level exclusive scan of cnt -> off ----------------
__global__ void scan1(const int* __restrict__ cnt, int* __restrict__ off,
                      int* __restrict__ bsums, int N) {
    __shared__ int s[256];
    int i = blockIdx.x * 256 + threadIdx.x;
    int v = (i < N) ? cnt[i] : 0;
    s[threadIdx.x] = v;
    __syncthreads();
    for (int d = 1; d < 256; d <<= 1) {
        int t = (threadIdx.x >= d) ? s[threadIdx.x - d] : 0;
        __syncthreads();
        s[threadIdx.x] += t;
        __syncthreads();
    }
    if (i < N) off[i] = s[threadIdx.x] - v;  // exclusive
    if (threadIdx.x == 255) bsums[blockIdx.x] = s[255];
}

__global__ void scan2(int* __restrict__ bsums, int nb) {
    __shared__ int s[512];
    int tid = threadIdx.x;
    int v = (tid < nb) ? bsums[tid] : 0;
    s[tid] = v;
    __syncthreads();
    for (int d = 1; d < 512; d <<= 1) {
        int t = (tid >= d) ? s[tid - d] : 0;
        __syncthreads();
        s[tid] += t;
        __syncthreads();
    }
    if (tid < nb) bsums[tid] = s[tid] - v;  // exclusive block offsets
}

__global__ void scan3(int* __restrict__ off, const int* __restrict__ bsums,
                      int* __restrict__ cursor, int N, int E) {
    int i = blockIdx.x * 256 + threadIdx.x;
    if (i < N) {
        int v = off[i] + bsums[blockIdx.x];
        off[i] = v;
        cursor[i] = v;
    }
    if (blockIdx.x == 0 && threadIdx.x == 0) off[N] = E;
}

// ---------------- CSR bucket fill (fuses norm computation) ----------------
__global__ void build_csr(const int* __restrict__ src, const int* __restrict__ dst,
                          const float* __restrict__ ew, const float* __restrict__ dinv,
                          int* __restrict__ cursor, int2* __restrict__ pair, int E) {
    int e = blockIdx.x * blockDim.x + threadIdx.x;
    int stride = gridDim.x * blockDim.x;
    for (; e < E; e += stride) {
        int s = src[e];
        int d = dst[e];
        float w = dinv[s] * ew[e] * dinv[d];
        int pos = atomicAdd(&cursor[d], 1);
        pair[pos] = make_int2(s, __float_as_int(w));
    }
}

// ---------------- GEMM: X[N,K] @ W[K,64] -> H[N,64] ----------------
template <int K>
__global__ __launch_bounds__(256) void gemm_x64(const float* __restrict__ X,
                                                const float* __restrict__ W,
                                                float* __restrict__ H, int N) {
    __shared__ float Ws[K * 64];
    for (int idx = threadIdx.x; idx < K * 64 / 4; idx += 256)
        ((float4*)Ws)[idx] = ((const float4*)W)[idx];
    __syncthreads();

    const int tr = threadIdx.x >> 4;
    const int tc = threadIdx.x & 15;
    const int rowBase = blockIdx.x * 64 + tr * 4;

    float4 acc[4];
    #pragma unroll
    for (int i = 0; i < 4; i++) acc[i] = make_float4(0.f, 0.f, 0.f, 0.f);

    const float4* X4 = (const float4*)X;
    const float4* Ws4 = (const float4*)Ws;
    bool v[4];
    #pragma unroll
    for (int i = 0; i < 4; i++) v[i] = (rowBase + i) < N;

    for (int kk = 0; kk < K; kk += 4) {
        float4 a[4];
        #pragma unroll
        for (int i = 0; i < 4; i++)
            a[i] = v[i] ? X4[(ll)(rowBase + i) * (K / 4) + (kk >> 2)]
                        : make_float4(0.f, 0.f, 0.f, 0.f);
        #pragma unroll
        for (int t = 0; t < 4; t++) {
            float4 b = Ws4[(kk + t) * 16 + tc];
            #pragma unroll
            for (int i = 0; i < 4; i++) {
                float av = (t == 0) ? a[i].x : (t == 1) ? a[i].y : (t == 2) ? a[i].z : a[i].w;
                acc[i].x += av * b.x;
                acc[i].y += av * b.y;
                acc[i].z += av * b.z;
                acc[i].w += av * b.w;
            }
        }
    }
    float4* H4 = (float4*)H;
    #pragma unroll
    for (int i = 0; i < 4; i++)
        if (v[i]) H4[(ll)(rowBase + i) * 16 + tc] = acc[i];
}

// ---------------- GEMM: X[N,64] @ W[64,16] -> H[N,16] ----------------
__global__ __launch_bounds__(256) void gemm_64x16(const float* __restrict__ X,
                                                  const float* __restrict__ W,
                                                  float* __restrict__ H, int N) {
    __shared__ float Ws[64 * 16];
    for (int idx = threadIdx.x; idx < 64 * 16 / 4; idx += 256)
        ((float4*)Ws)[idx] = ((const float4*)W)[idx];
    __syncthreads();

    const int tr = threadIdx.x >> 2;
    const int tc = threadIdx.x & 3;
    const int row = blockIdx.x * 64 + tr;
    if (row >= N) return;

    float4 acc = make_float4(0.f, 0.f, 0.f, 0.f);
    const float4* X4 = (const float4*)X;
    const float4* Ws4 = (const float4*)Ws;
    for (int kk = 0; kk < 64; kk += 4) {
        float4 a = X4[(ll)row * 16 + (kk >> 2)];
        #pragma unroll
        for (int t = 0; t < 4; t++) {
            float4 b = Ws4[(kk + t) * 4 + tc];
            float av = (t == 0) ? a.x : (t == 1) ? a.y : (t == 2) ? a.z : a.w;
            acc.x += av * b.x;
            acc.y += av * b.y;
            acc.z += av * b.z;
            acc.w += av * b.w;
        }
    }
    ((float4*)H)[(ll)row * 4 + tc] = acc;
}

// ---------------- CSR gather, F=64: one wave per node, fused epilogue ----------------
template <bool RELU>
__global__ __launch_bounds__(256) void gather64(const float* __restrict__ h,
                                                const int2* __restrict__ pair,
                                                const int* __restrict__ off,
                                                const float* __restrict__ dinv,
                                                const float* __restrict__ bias,
                                                float* __restrict__ outb, int N) {
    int node = blockIdx.x * 4 + (threadIdx.x >> 6);
    int lane = threadIdx.x & 63;
    if (node >= N) return;
    int e0 = off[node];
    int e1 = off[node + 1];

    float acc = 0.f;
    int e = e0;
    for (; e + 1 < e1; e += 2) {
        int2 p0 = pair[e];
        int2 p1 = pair[e + 1];
        float v0 = h[(ll)p0.x * 64 + lane];
        float v1 = h[(ll)p1.x * 64 + lane];
        acc += v0 * __int_as_float(p0.y);
        acc += v1 * __int_as_float(p1.y);
    }
    if (e < e1) {
        int2 p = pair[e];
        acc += h[(ll)p.x * 64 + lane] * __int_as_float(p.y);
    }

    float di = dinv[node];
    float r = acc + h[(ll)node * 64 + lane] * (di * di) + bias[lane];
    if (RELU) r = fmaxf(r, 0.f);
    outb[(ll)node * 64 + lane] = r;
}

// ---------------- CSR gather F=16 + log_softmax, 16 lanes per node ----------------
__global__ __launch_bounds__(256) void gather16_final(const float* __restrict__ h3,
                                                      const int2* __restrict__ pair,
                                                      const int* __restrict__ off,
                                                      const float* __restrict__ dinv,
                                                      const float* __restrict__ b3,
                                                      float* __restrict__ out, int N) {
    int node = blockIdx.x * 16 + (threadIdx.x >> 4);
    int lane = threadIdx.x & 15;
    if (node >= N) return;
    int e0 = off[node];
    int e1 = off[node + 1];

    float acc = 0.f;
    int e = e0;
    for (; e + 1 < e1; e += 2) {
        int2 p0 = pair[e];
        int2 p1 = pair[e + 1];
        float v0 = h3[(ll)p0.x * 16 + lane];
        float v1 = h3[(ll)p1.x * 16 + lane];
        acc += v0 * __int_as_float(p0.y);
        acc += v1 * __int_as_float(p1.y);
    }
    if (e < e1) {
        int2 p = pair[e];
        acc += h3[(ll)p.x * 16 + lane] * __int_as_float(p.y);
    }

    float di = dinv[node];
    float z = acc + h3[(ll)node * 16 + lane] * (di * di) + b3[lane];

    float m = z;
    #pragma unroll
    for (int o = 8; o; o >>= 1) m = fmaxf(m, __shfl_xor(m, o, 16));
    float s = expf(z - m);
    #pragma unroll
    for (int o = 8; o; o >>= 1) s += __shfl_xor(s, o, 16);
    out[(ll)node * 16 + lane] = z - m - logf(s);
}

extern "C" void kernel_launch(void* const* d_in, const int* in_sizes, int n_in,
                              void* d_out, int out_size, void* d_ws, size_t ws_size,
                              hipStream_t stream) {
    const float* x = (const float*)d_in[0];
    const int* ei = (const int*)d_in[1];
    const float* ew = (const float*)d_in[2];
    const float* W1 = (const float*)d_in[3];
    const float* b1 = (const float*)d_in[4];
    const float* W2 = (const float*)d_in[5];
    const float* b2 = (const float*)d_in[6];
    const float* W3 = (const float*)d_in[7];
    const float* b3 = (const float*)d_in[8];

    const int N = in_sizes[0] / DIN;
    const int E = in_sizes[2];
    const int* src = ei;
    const int* dst = ei + E;

    float* out = (float*)d_out;

    // workspace layout (4-byte units); pair first for 8B alignment
    float* A = (float*)d_ws;                 // [N,64] h buffer
    float* B = A + (ll)N * DH;               // [N,64] agg buffer
    int2* pair = (int2*)(B + (ll)N * DH);    // [E] (src, norm) sorted by dst
    float* dinv = (float*)(pair + E);        // [N] deg -> dinv in place
    int* cnt = (int*)(dinv + N);             // [N] count -> cursor
    int* off = cnt + N;                      // [N+1] CSR offsets
    int* bsums = off + N + 1;                // [512]

    const int TB = 256;
    const int edgeBlocks = (E + TB - 1) / TB;
    const int nodeBlocks = (N + TB - 1) / TB;
    const int rowBlocks = (N + 63) / 64;
    const int nb = nodeBlocks;  // scan blocks (<=512 required; 391 here)

    // --- degrees, dinv, CSR offsets ---
    hipMemsetAsync(dinv, 0, (size_t)(2 * N) * sizeof(float), stream);  // deg + cnt
    deg_kernel<<<edgeBlocks, TB, 0, stream>>>(dst, ew, dinv, cnt, E);
    dinv_kernel<<<nodeBlocks, TB, 0, stream>>>(dinv, N);
    scan1<<<nb, TB, 0, stream>>>(cnt, off, bsums, N);
    scan2<<<1, 512, 0, stream>>>(bsums, nb);
    scan3<<<nb, TB, 0, stream>>>(off, bsums, cnt, N, E);
    build_csr<<<edgeBlocks, TB, 0, stream>>>(src, dst, ew, dinv, cnt, pair, E);

    // --- layer 1 ---
    gemm_x64<DIN><<<rowBlocks, TB, 0, stream>>>(x, W1, A, N);
    gather64<true><<<(N + 3) / 4, TB, 0, stream>>>(A, pair, off, dinv, b1, B, N);

    // --- layer 2 ---
    gemm_x64<DH><<<rowBlocks, TB, 0, stream>>>(B, W2, A, N);
    gather64<true><<<(N + 3) / 4, TB, 0, stream>>>(A, pair, off, dinv, b2, B, N);

    // --- layer 3 ---
    gemm_64x16<<<rowBlocks, TB, 0, stream>>>(B, W3, A, N);  // h3 -> A [N,16]
    gather16_final<<<(N + 15) / 16, TB, 0, stream>>>(A, pair, off, dinv, b3, out, N);
}